// Round 6
// baseline (89.503 us; speedup 1.0000x reference)
//
#include <hip/hip_runtime.h>
#include <hip/hip_bf16.h>

// ContrastiveLoss: N=8192, D=256, NUM_IDS=1000, MARGIN=0.3
// R6: LDS-staged GEMM with counted-vmcnt pipeline (T3+T4), raw s_barrier
// (no __syncthreads vmcnt(0) drain in the K-loop). 128^2 tile, 4 waves,
// BK=32, 3 rotating LDS buffers (2-tile lookahead), 32x32x16 MFMA.
// Epilogue and tri-decode verbatim from verified R5.

#define MARGINF 0.3f

typedef __attribute__((ext_vector_type(8))) short short8x;    // 8 bf16 (4 VGPRs)
typedef __attribute__((ext_vector_type(16))) float f32x16;    // 16 fp32 acc

// ---------- round-to-nearest-even f32 -> bf16 bits ----------
__device__ __forceinline__ unsigned short f2bf(float f) {
    unsigned int u = __float_as_uint(f);
    unsigned int r = (u + 0x7fffu + ((u >> 16) & 1u)) >> 16;
    return (unsigned short)r;
}

// ---------- pass 1: fp32 -> bf16 row-major convert (verified R1/R2) ----------
__global__ void __launch_bounds__(256) convert_k(const float* __restrict__ x,
                                                 unsigned short* __restrict__ xb) {
    int i = blockIdx.x * 256 + threadIdx.x;          // 0 .. 262143
    const float4* p = reinterpret_cast<const float4*>(x) + (size_t)i * 2;
    float4 a = p[0];
    float4 b = p[1];
    short8x o;
    o[0] = (short)f2bf(a.x); o[1] = (short)f2bf(a.y);
    o[2] = (short)f2bf(a.z); o[3] = (short)f2bf(a.w);
    o[4] = (short)f2bf(b.x); o[5] = (short)f2bf(b.y);
    o[6] = (short)f2bf(b.z); o[7] = (short)f2bf(b.w);
    reinterpret_cast<short8x*>(xb)[i] = o;
}

// ---------- pass 2: pipelined LDS GEMM + contrastive loss ----------
// LDS buffer layout: 3 bufs x 16KB; per buf: A[128 rows][64B] at +0,
// B[128][64B] at +8192. 16B chunk swizzle: stored chunk c' = c ^ ((row>>1)&3),
// applied on stage SOURCE and ds_read address (linear LDS dest for gll).
__global__ void __launch_bounds__(256, 3) gemm_loss_k(const unsigned short* __restrict__ xb,
                                                      const int* __restrict__ tg,
                                                      double* __restrict__ partials) {
    // ---- 1D upper-triangle decode: p -> (bi <= bj), 64x64 tile grid ----
    const int p = blockIdx.x;
    int bi = (int)(64.5f - sqrtf(64.5f * 64.5f - 2.0f * (float)p));
    if (bi < 0) bi = 0;
    if (bi > 63) bi = 63;
    while (bi > 0 && (bi * (129 - bi)) / 2 > p) --bi;
    while (((bi + 1) * (128 - bi)) / 2 <= p) ++bi;
    const int bj = bi + (p - (bi * (129 - bi)) / 2);

    __shared__ __align__(16) char ldsb[3 * 16384];
    __shared__ int lti[128];
    __shared__ int ltj[128];
    __shared__ float redbuf[4];

    const int tid  = threadIdx.x;
    const int lane = tid & 63;
    const int wid  = tid >> 6;       // 0..3
    const int wr   = wid >> 1;       // wave row (0..1)
    const int wc   = wid & 1;        // wave col (0..1)

    if (tid < 128)       lti[tid]        = tg[bi * 128 + tid];
    else                 ltj[tid - 128]  = tg[bj * 128 + (tid - 128)];
    __syncthreads();   // labels visible; no global_load_lds outstanding yet

    const char* aBase = (const char*)(xb + (size_t)bi * 128 * 256);
    const char* bBase = (const char*)(xb + (size_t)bj * 128 * 256);

    // ---- stage addressing: thread t writes LDS byte i*4096 + t*16 ----
    // row r = i*64 + (t>>2); stored chunk c' = t&3; source chunk = c' ^ ((r>>1)&3)
    // (r>>1)&3 == (lane>>3)&3 (wid*8, i*32 are 0 mod 4)
    const int srow0  = wid * 16 + (lane >> 2);
    const int schunk = (((lane & 3) ^ ((lane >> 3) & 3))) << 4;

    // ---- ds_read offsets: frag row r = base + (lane&31); swz = (r>>1)&3 = ((lane&31)>>1)&3
    const int l31 = lane & 31;
    const int hi  = lane >> 5;
    const int swz = (l31 >> 1) & 3;
    int offA[2][2], offB[2][2];
#pragma unroll
    for (int fm = 0; fm < 2; ++fm)
#pragma unroll
        for (int ks = 0; ks < 2; ++ks)
            offA[fm][ks] = (wr * 64 + fm * 32 + l31) * 64 + ((((ks << 1) | hi) ^ swz) << 4);
#pragma unroll
    for (int fn = 0; fn < 2; ++fn)
#pragma unroll
        for (int ks = 0; ks < 2; ++ks)
            offB[fn][ks] = 8192 + (wc * 64 + fn * 32 + l31) * 64 + ((((ks << 1) | hi) ^ swz) << 4);

    f32x16 acc00 = {}, acc01 = {}, acc10 = {}, acc11 = {};

#define STAGE_KT(BUF, T) do {                                                        \
    _Pragma("unroll")                                                                \
    for (int i_ = 0; i_ < 2; ++i_) {                                                 \
        const int r_ = i_ * 64 + srow0;                                              \
        const char* sa_ = aBase + (size_t)r_ * 512 + (T) * 64 + schunk;              \
        const char* sb_ = bBase + (size_t)r_ * 512 + (T) * 64 + schunk;              \
        __builtin_amdgcn_global_load_lds(                                            \
            (const __attribute__((address_space(1))) unsigned int*)sa_,              \
            (__attribute__((address_space(3))) unsigned int*)(ldsb + (BUF) * 16384 + i_ * 4096 + wid * 1024), \
            16, 0, 0);                                                               \
        __builtin_amdgcn_global_load_lds(                                            \
            (const __attribute__((address_space(1))) unsigned int*)sb_,              \
            (__attribute__((address_space(3))) unsigned int*)(ldsb + (BUF) * 16384 + 8192 + i_ * 4096 + wid * 1024), \
            16, 0, 0);                                                               \
    }                                                                                \
} while (0)

#define GEMM_ITER(T, BUF, VMSTR, DOSTAGE) do {                                       \
    asm volatile("s_waitcnt vmcnt(" VMSTR ")" ::: "memory");                         \
    __builtin_amdgcn_s_barrier();                 /* KT T visible to all waves */    \
    const char* lb_ = ldsb + (BUF) * 16384;                                          \
    short8x a0k0 = *(const short8x*)(lb_ + offA[0][0]);                              \
    short8x a1k0 = *(const short8x*)(lb_ + offA[1][0]);                              \
    short8x b0k0 = *(const short8x*)(lb_ + offB[0][0]);                              \
    short8x b1k0 = *(const short8x*)(lb_ + offB[1][0]);                              \
    short8x a0k1 = *(const short8x*)(lb_ + offA[0][1]);                              \
    short8x a1k1 = *(const short8x*)(lb_ + offA[1][1]);                              \
    short8x b0k1 = *(const short8x*)(lb_ + offB[0][1]);                              \
    short8x b1k1 = *(const short8x*)(lb_ + offB[1][1]);                              \
    asm volatile("s_waitcnt lgkmcnt(0)" ::: "memory");                               \
    __builtin_amdgcn_sched_barrier(0);                                               \
    __builtin_amdgcn_s_barrier();                 /* all waves done reading BUF */   \
    if (DOSTAGE) STAGE_KT(BUF, (T) + 3);          /* refill freed buffer */          \
    __builtin_amdgcn_s_setprio(1);                                                   \
    acc00 = __builtin_amdgcn_mfma_f32_32x32x16_bf16(a0k0, b0k0, acc00, 0, 0, 0);     \
    acc01 = __builtin_amdgcn_mfma_f32_32x32x16_bf16(a0k0, b1k0, acc01, 0, 0, 0);     \
    acc10 = __builtin_amdgcn_mfma_f32_32x32x16_bf16(a1k0, b0k0, acc10, 0, 0, 0);     \
    acc11 = __builtin_amdgcn_mfma_f32_32x32x16_bf16(a1k0, b1k0, acc11, 0, 0, 0);     \
    acc00 = __builtin_amdgcn_mfma_f32_32x32x16_bf16(a0k1, b0k1, acc00, 0, 0, 0);     \
    acc01 = __builtin_amdgcn_mfma_f32_32x32x16_bf16(a0k1, b1k1, acc01, 0, 0, 0);     \
    acc10 = __builtin_amdgcn_mfma_f32_32x32x16_bf16(a1k1, b0k1, acc10, 0, 0, 0);     \
    acc11 = __builtin_amdgcn_mfma_f32_32x32x16_bf16(a1k1, b1k1, acc11, 0, 0, 0);     \
    __builtin_amdgcn_s_setprio(0);                                                   \
} while (0)

    // prologue: stage KT0..KT2 (12 loads in flight)
    STAGE_KT(0, 0);
    STAGE_KT(1, 1);
    STAGE_KT(2, 2);

    // 8 K-tiles; vmcnt ladder keeps 2 tiles in flight until drain
    GEMM_ITER(0, 0, "8", 1);
    GEMM_ITER(1, 1, "8", 1);
    GEMM_ITER(2, 2, "8", 1);
    GEMM_ITER(3, 0, "8", 1);
    GEMM_ITER(4, 1, "8", 1);
    GEMM_ITER(5, 2, "8", 0);
    GEMM_ITER(6, 0, "4", 0);
    GEMM_ITER(7, 1, "0", 0);

#undef GEMM_ITER
#undef STAGE_KT

    // ---- epilogue: masks + loss (verified R5) ----
    // 32x32 C/D layout (m74/m101): col = lane&31, row = (reg&3)+8*(reg>>2)+4*(lane>>5)
    const int hi4 = hi * 4;
    const int col_l = l31;
    int tjv[2];
#pragma unroll
    for (int fn = 0; fn < 2; ++fn) tjv[fn] = ltj[wc * 64 + fn * 32 + col_l];

    float lsum = 0.f;
    const f32x16* accs[4] = { &acc00, &acc01, &acc10, &acc11 };

    if (bi != bj) {
        // off-diagonal tile: every element counts twice (symmetry)
#pragma unroll
        for (int fm = 0; fm < 2; ++fm) {
#pragma unroll
            for (int fn = 0; fn < 2; ++fn) {
                const f32x16& A = *accs[fm * 2 + fn];
                const int tj = tjv[fn];
#pragma unroll
                for (int r = 0; r < 16; ++r) {
                    const int row_l = (r & 3) + 8 * (r >> 2) + hi4;
                    const int ti = lti[wr * 64 + fm * 32 + row_l];
                    const float s = A[r];
                    const float posv = fmaxf(1.0f - s, 0.0f);
                    const float negv = (s > MARGINF) ? s : 0.0f;
                    lsum += (ti == tj) ? posv : negv;
                }
            }
        }
        lsum *= 2.0f;
    } else {
        // diagonal tile: strict-upper x2, diagonal x1, lower x0
#pragma unroll
        for (int fm = 0; fm < 2; ++fm) {
#pragma unroll
            for (int fn = 0; fn < 2; ++fn) {
                const f32x16& A = *accs[fm * 2 + fn];
                const int tj = tjv[fn];
                const int cl = wc * 64 + fn * 32 + col_l;
#pragma unroll
                for (int r = 0; r < 16; ++r) {
                    const int row_l = (r & 3) + 8 * (r >> 2) + hi4;
                    const int rl = wr * 64 + fm * 32 + row_l;
                    const int ti = lti[rl];
                    const float s = A[r];
                    const float posv = fmaxf(1.0f - s, 0.0f);
                    const float negv = (s > MARGINF) ? s : 0.0f;
                    const float c = (ti == tj) ? posv : negv;
                    const float w = (cl > rl) ? 2.0f : ((cl == rl) ? 1.0f : 0.0f);
                    lsum += w * c;
                }
            }
        }
    }

    // wave reduce then cross-wave
#pragma unroll
    for (int mask = 1; mask < 64; mask <<= 1) lsum += __shfl_xor(lsum, mask, 64);
    if (lane == 0) redbuf[wid] = lsum;
    __syncthreads();
    if (tid == 0)
        partials[p] = (double)(redbuf[0] + redbuf[1] + redbuf[2] + redbuf[3]);
}

// ---------- pass 3: sum partials, divide by N ----------
__global__ void __launch_bounds__(256) finalize_k(const double* __restrict__ partials,
                                                  float* __restrict__ out) {
    double s = 0.0;
    for (int i = threadIdx.x; i < 2080; i += 256) s += partials[i];
#pragma unroll
    for (int mask = 1; mask < 64; mask <<= 1) s += __shfl_xor(s, mask, 64);
    __shared__ double red[4];
    const int wid = threadIdx.x >> 6;
    if ((threadIdx.x & 63) == 0) red[wid] = s;
    __syncthreads();
    if (threadIdx.x == 0)
        out[0] = (float)((red[0] + red[1] + red[2] + red[3]) / 8192.0);
}

extern "C" void kernel_launch(void* const* d_in, const int* in_sizes, int n_in,
                              void* d_out, int out_size, void* d_ws, size_t ws_size,
                              hipStream_t stream) {
    (void)in_sizes; (void)n_in; (void)out_size; (void)ws_size;
    const float* x  = (const float*)d_in[0];
    const int*   tg = (const int*)d_in[1];
    float* out = (float*)d_out;

    double* partials   = (double*)d_ws;                          // 2080 * 8B
    unsigned short* xb = (unsigned short*)((char*)d_ws + 32768); // 4MB bf16 X (row-major)

    convert_k<<<1024, 256, 0, stream>>>(x, xb);
    gemm_loss_k<<<2080, 256, 0, stream>>>(xb, tg, partials);
    finalize_k<<<1, 256, 0, stream>>>(partials, out);
}